// Round 1
// baseline (319.556 us; speedup 1.0000x reference)
//
#include <hip/hip_runtime.h>
#include <hip/hip_bf16.h>

#define NB 128
#define NS 101
#define NW 1024
#define OH 200
#define OW 200

// ---- sortable-uint encode for float atomics ----
__device__ __forceinline__ unsigned encf(float f) {
    unsigned u = __float_as_uint(f);
    return (u & 0x80000000u) ? ~u : (u | 0x80000000u);
}
__device__ __forceinline__ float decf(unsigned e) {
    unsigned u = (e & 0x80000000u) ? (e ^ 0x80000000u) : ~e;
    return __uint_as_float(u);
}

// mm[0..127] = per-batch min slot, mm[128..255] = per-batch max slot
__global__ void init_minmax(unsigned* mm) {
    int t = threadIdx.x;
    if (t < NB) mm[t] = 0xFFFFFFFFu;      // min slot: +inf encoded
    else if (t < 2 * NB) mm[t] = 0u;      // max slot: -inf encoded
}

// Conv: res[b,s,w] = sum_u K[s,u] * xP[b, 1024 + w - u],
// xP = x zero-padded: xP[i] = x[i-512] for i in [512,1536).
// Grid: (NB, 8). Each WG: batch b, scale-pairs p == blockIdx.y (mod 8).
// Each thread: 4 consecutive w (w = 4*tid) x 2 scales.
__global__ __launch_bounds__(256) void conv_kernel(
        const float* __restrict__ x, const float* __restrict__ K,
        __hip_bfloat16* __restrict__ res, unsigned* __restrict__ mm) {
    __shared__ float xP[2048];
    const int b = blockIdx.x;
    const int q = blockIdx.y;
    const int tid = threadIdx.x;

    // stage padded signal into LDS (vectorized, aligned: 512/1536 are mult of 8)
    {
        float4 z = make_float4(0.f, 0.f, 0.f, 0.f);
        float4 v0 = z, v1 = z;
        if (tid >= 64 && tid < 192) {
            const float4* xs = (const float4*)(x + (size_t)b * NW + tid * 8 - 512);
            v0 = xs[0];
            v1 = xs[1];
        }
        float4* xp4w = (float4*)xP;
        xp4w[tid * 2]     = v0;
        xp4w[tid * 2 + 1] = v1;
    }
    __syncthreads();

    float mnT = 3.4e38f, mxT = -3.4e38f;
    const float4* xp4 = (const float4*)xP;
    const int w0 = tid * 4;

    for (int p = q; p <= 50; p += 8) {
        const int s0 = 2 * p;
        const int s1 = (2 * p + 1 <= 100) ? (2 * p + 1) : 100;
        const float scale1 = 4.0f + (float)s1;
        int hw = (int)(6.0f * scale1) + 2;
        if (hw > 512) hw = 512;
        const int ulo = (512 - hw) & ~3;
        int uhi = 512 + hw;
        if (uhi > 1024) uhi = 1024;

        const float* K0 = K + (size_t)s0 * NW;
        const float* K1 = K + (size_t)s1 * NW;

        float a0 = 0.f, a1 = 0.f, a2 = 0.f, a3 = 0.f;
        float c0 = 0.f, c1 = 0.f, c2 = 0.f, c3 = 0.f;

        int Bq = (1024 + w0 - ulo) >> 2;     // float4 index of xP[B..B+3]
        float4 xb = xp4[Bq];
        #pragma unroll 2
        for (int u0 = ulo; u0 < uhi; u0 += 4) {
            const float4 xa = xp4[Bq - 1];   // xP[B-4..B-1]
            const float4 k4 = *(const float4*)(K0 + u0);
            const float4 g4 = *(const float4*)(K1 + u0);
            // acc[d] += k[c] * xP[B + d - c]
            a0 = fmaf(k4.x, xb.x, a0); a0 = fmaf(k4.y, xa.w, a0); a0 = fmaf(k4.z, xa.z, a0); a0 = fmaf(k4.w, xa.y, a0);
            a1 = fmaf(k4.x, xb.y, a1); a1 = fmaf(k4.y, xb.x, a1); a1 = fmaf(k4.z, xa.w, a1); a1 = fmaf(k4.w, xa.z, a1);
            a2 = fmaf(k4.x, xb.z, a2); a2 = fmaf(k4.y, xb.y, a2); a2 = fmaf(k4.z, xb.x, a2); a2 = fmaf(k4.w, xa.w, a2);
            a3 = fmaf(k4.x, xb.w, a3); a3 = fmaf(k4.y, xb.z, a3); a3 = fmaf(k4.z, xb.y, a3); a3 = fmaf(k4.w, xb.x, a3);
            c0 = fmaf(g4.x, xb.x, c0); c0 = fmaf(g4.y, xa.w, c0); c0 = fmaf(g4.z, xa.z, c0); c0 = fmaf(g4.w, xa.y, c0);
            c1 = fmaf(g4.x, xb.y, c1); c1 = fmaf(g4.y, xb.x, c1); c1 = fmaf(g4.z, xa.w, c1); c1 = fmaf(g4.w, xa.z, c1);
            c2 = fmaf(g4.x, xb.z, c2); c2 = fmaf(g4.y, xb.y, c2); c2 = fmaf(g4.z, xb.x, c2); c2 = fmaf(g4.w, xa.w, c2);
            c3 = fmaf(g4.x, xb.w, c3); c3 = fmaf(g4.y, xb.z, c3); c3 = fmaf(g4.z, xb.y, c3); c3 = fmaf(g4.w, xb.x, c3);
            xb = xa;
            --Bq;
        }

        // store rows (8B-aligned ushort4)
        {
            union { ushort4 u4; __hip_bfloat16 h[4]; } pk;
            pk.h[0] = __float2bfloat16(a0); pk.h[1] = __float2bfloat16(a1);
            pk.h[2] = __float2bfloat16(a2); pk.h[3] = __float2bfloat16(a3);
            *(ushort4*)(res + ((size_t)b * NS + s0) * NW + w0) = pk.u4;
            pk.h[0] = __float2bfloat16(c0); pk.h[1] = __float2bfloat16(c1);
            pk.h[2] = __float2bfloat16(c2); pk.h[3] = __float2bfloat16(c3);
            *(ushort4*)(res + ((size_t)b * NS + s1) * NW + w0) = pk.u4;
        }
        mnT = fminf(mnT, fminf(fminf(a0, a1), fminf(a2, a3)));
        mxT = fmaxf(mxT, fmaxf(fmaxf(a0, a1), fmaxf(a2, a3)));
        if (s1 != s0) {
            mnT = fminf(mnT, fminf(fminf(c0, c1), fminf(c2, c3)));
            mxT = fmaxf(mxT, fmaxf(fmaxf(c0, c1), fmaxf(c2, c3)));
        }
    }

    // reduce min/max: wave shuffle then LDS then one atomic per WG
    for (int off = 32; off > 0; off >>= 1) {
        mnT = fminf(mnT, __shfl_down(mnT, off));
        mxT = fmaxf(mxT, __shfl_down(mxT, off));
    }
    __shared__ float smn[4], smx[4];
    const int wid = tid >> 6, lane = tid & 63;
    if (lane == 0) { smn[wid] = mnT; smx[wid] = mxT; }
    __syncthreads();
    if (tid == 0) {
        float mn = fminf(fminf(smn[0], smn[1]), fminf(smn[2], smn[3]));
        float mx = fmaxf(fmaxf(smx[0], smx[1]), fmaxf(smx[2], smx[3]));
        atomicMin(&mm[b], encf(mn));
        atomicMax(&mm[NB + b], encf(mx));
    }
}

// Bilinear resize (101,1024)->(200,200) with jax.image.resize semantics
// (antialias=False): coord = (i+0.5)*in/out - 0.5, 2 taps clamped.
__global__ __launch_bounds__(256) void resize_kernel(
        const __hip_bfloat16* __restrict__ res, const unsigned* __restrict__ mm,
        float* __restrict__ out) {
    const int idx = blockIdx.x * 256 + threadIdx.x;
    if (idx >= NB * OH * OW) return;
    const int j = idx % OW;
    const int rem = idx / OW;
    const int i = rem % OH;
    const int b = rem / OH;

    const float mn = decf(mm[b]);
    const float mx = decf(mm[NB + b]);
    const float inv = 1.0f / (mx - mn);

    const float y = (i + 0.5f) * (101.0f / 200.0f) - 0.5f;
    const float xx = (j + 0.5f) * (1024.0f / 200.0f) - 0.5f;
    const float yf = floorf(y), xf = floorf(xx);
    const float fy = y - yf, fx = xx - xf;
    int i0 = (int)yf, j0 = (int)xf;
    int i1 = i0 + 1, j1 = j0 + 1;
    i0 = max(0, min(NS - 1, i0)); i1 = max(0, min(NS - 1, i1));
    j0 = max(0, min(NW - 1, j0)); j1 = max(0, min(NW - 1, j1));

    const __hip_bfloat16* rb = res + (size_t)b * NS * NW;
    const float v00 = __bfloat162float(rb[i0 * NW + j0]);
    const float v01 = __bfloat162float(rb[i0 * NW + j1]);
    const float v10 = __bfloat162float(rb[i1 * NW + j0]);
    const float v11 = __bfloat162float(rb[i1 * NW + j1]);
    const float v = (1.f - fy) * ((1.f - fx) * v00 + fx * v01)
                  + fy * ((1.f - fx) * v10 + fx * v11);
    out[idx] = (v - mn) * inv;
}

extern "C" void kernel_launch(void* const* d_in, const int* in_sizes, int n_in,
                              void* d_out, int out_size, void* d_ws, size_t ws_size,
                              hipStream_t stream) {
    const float* x = (const float*)d_in[0];   // (128,1024) f32
    const float* K = (const float*)d_in[1];   // (101,1024) f32
    float* out = (float*)d_out;               // (128,200,200,1) f32

    __hip_bfloat16* res = (__hip_bfloat16*)d_ws;                       // 26.5 MB
    unsigned* mm = (unsigned*)((char*)d_ws + (size_t)NB * NS * NW * 2); // 1 KB

    hipLaunchKernelGGL(init_minmax, dim3(1), dim3(256), 0, stream, mm);
    hipLaunchKernelGGL(conv_kernel, dim3(NB, 8), dim3(256), 0, stream, x, K, res, mm);
    const int total = NB * OH * OW;
    hipLaunchKernelGGL(resize_kernel, dim3((total + 255) / 256), dim3(256), 0, stream,
                       res, mm, out);
}

// Round 2
// 131.231 us; speedup vs baseline: 2.4351x; 2.4351x over previous
//
#include <hip/hip_runtime.h>
#include <hip/hip_bf16.h>

#define NB 128
#define NS 101
#define NW 1024
#define OH 200
#define OW 200

typedef __bf16 bf16x8 __attribute__((ext_vector_type(8)));
typedef float f32x4 __attribute__((ext_vector_type(4)));

__device__ __forceinline__ void gload_lds16(const void* gsrc, void* ldst) {
    __builtin_amdgcn_global_load_lds(
        (const __attribute__((address_space(1))) void*)gsrc,
        (__attribute__((address_space(3))) void*)ldst, 16, 0, 0);
}

// ---- sortable-uint encode for float atomics ----
__device__ __forceinline__ unsigned encf(float f) {
    unsigned u = __float_as_uint(f);
    return (u & 0x80000000u) ? ~u : (u | 0x80000000u);
}
__device__ __forceinline__ float decf(unsigned e) {
    unsigned u = (e & 0x80000000u) ? (e ^ 0x80000000u) : ~e;
    return __uint_as_float(u);
}

// truncation range (compile-time foldable when t is constant)
__device__ __forceinline__ void trange(int t, int& lo, int& hi) {
    int smax = 19 + 16 * t; if (smax > 104) smax = 104;
    int hw = 6 * smax + 2;                    // envelope support half-width (+margin)
    int lo_ = (481 - hw + 31) / 32; if (lo_ < 0) lo_ = 0;
    int hi_ = (511 + hw) / 32;      if (hi_ > 31) hi_ = 31;
    lo = lo_; hi = hi_;
}

// prep: Kbf[112][1024] bf16 (rows >=101 zero) + init per-batch min/max slots
__global__ __launch_bounds__(256) void prep_kernel(const float* __restrict__ K,
                                                   ushort* __restrict__ Kbf,
                                                   unsigned* __restrict__ mm) {
    int blk = blockIdx.x;
    if (blk < 112) {
        int c = threadIdx.x * 4;
        float4 v = make_float4(0.f, 0.f, 0.f, 0.f);
        if (blk < NS) v = *(const float4*)(K + (size_t)blk * NW + c);
        ushort4 o;
        __hip_bfloat16 h;
        h = __float2bfloat16(v.x); o.x = reinterpret_cast<const ushort&>(h);
        h = __float2bfloat16(v.y); o.y = reinterpret_cast<const ushort&>(h);
        h = __float2bfloat16(v.z); o.z = reinterpret_cast<const ushort&>(h);
        h = __float2bfloat16(v.w); o.w = reinterpret_cast<const ushort&>(h);
        *(ushort4*)(Kbf + (size_t)blk * NW + c) = o;
    } else {
        int t = threadIdx.x;
        mm[t] = (t < NB) ? 0xFFFFFFFFu : 0u;
    }
}

// conv: res[b,s,w] = sum_u Kbf[s,u] * xP[b, 1024 + w - u] via MFMA implicit GEMM
// grid 512: blockIdx.x = b*4 + chunk(256 w). 4 waves: wave wv owns w-range
// wbase = chunk*256 + wv*64 (4 n-tiles of 16), all 7 s-tiles (112 rows).
__global__ __launch_bounds__(256) void conv_mfma(
        const float* __restrict__ x, const ushort* __restrict__ Kbf,
        __hip_bfloat16* __restrict__ res, unsigned* __restrict__ mm) {
    __shared__ __align__(16) ushort xSh[8 * 2056];       // 8 shifted copies of xR
    __shared__ __align__(16) ushort A_lds[2][7][512];    // dbuf, frag-major K tiles
    __shared__ float smn[4], smx[4];

    const int tid = threadIdx.x;
    const int b = blockIdx.x >> 2;
    const int chunk = blockIdx.x & 3;
    const int wv = tid >> 6;
    const int lane = tid & 63;
    const int n = lane & 15;
    const int g = lane >> 4;

    // ---- stage reversed signal, 8 shifted copies: xSh[d][i] = xR[i+d],
    //      xR[q] = x[1535-q] for q in [512,1536) else 0 ----
    {
        const float* xb = x + (size_t)b * NW;
        for (int idx = tid; idx < 8 * 257; idx += 256) {
            int dlt = idx / 257;
            int i0 = (idx % 257) * 8;
            union { ushort us[8]; uint4 v; } pk;
            #pragma unroll
            for (int j = 0; j < 8; ++j) {
                int ir = i0 + j + dlt;
                float f = (ir >= 512 && ir < 1536) ? xb[1535 - ir] : 0.0f;
                __hip_bfloat16 h = __float2bfloat16(f);
                pk.us[j] = reinterpret_cast<const ushort&>(h);
            }
            *reinterpret_cast<uint4*>(&xSh[dlt * 2056 + i0]) = pk.v;
        }
    }

    // ---- B-fragment base: lane reads xR[E0..E0+7] from shifted copy dlt,
    //      16B-aligned by construction (E0 ≡ dlt mod 8) ----
    const int dlt = (7 - n) & 7;
    const int wbase = chunk * 256 + wv * 64;
    const int eb0 = dlt * 2056 + (1023 - (wbase + n) + 8 * g - dlt);
    const ushort* bp = xSh + eb0;

    f32x4 acc[7][4];
    #pragma unroll
    for (int t = 0; t < 7; ++t)
        #pragma unroll
        for (int nt = 0; nt < 4; ++nt)
            acc[t][nt] = (f32x4){0.f, 0.f, 0.f, 0.f};

    // ---- A-tile prefetch: wave wv stages tiles {wv, wv+4} when active ----
    auto issueA = [&](int s, int buf) {
        #pragma unroll
        for (int tt = 0; tt < 2; ++tt) {
            int t = wv + tt * 4;
            if (t < 7) {
                int lo, hi; trange(t, lo, hi);
                if (s >= lo && s <= hi) {
                    const ushort* src = Kbf + ((size_t)(16 * t + n) * NW + 32 * s + 8 * g);
                    gload_lds16((const void*)src, (void*)&A_lds[buf][t][0]);
                }
            }
        }
    };

    issueA(0, 0);
    __syncthreads();   // xSh writes + step-0 A tiles complete

    for (int s = 0; s < 32; ++s) {
        if (s < 31) issueA(s + 1, (s + 1) & 1);

        bf16x8 bfr[4];
        #pragma unroll
        for (int nt = 0; nt < 4; ++nt)
            bfr[nt] = *reinterpret_cast<const bf16x8*>(bp + 32 * s - 16 * nt);

        #pragma unroll
        for (int t = 0; t < 7; ++t) {
            int lo, hi; trange(t, lo, hi);
            if (s >= lo && s <= hi) {
                bf16x8 af = *reinterpret_cast<const bf16x8*>(&A_lds[s & 1][t][lane * 8]);
                acc[t][0] = __builtin_amdgcn_mfma_f32_16x16x32_bf16(af, bfr[0], acc[t][0], 0, 0, 0);
                acc[t][1] = __builtin_amdgcn_mfma_f32_16x16x32_bf16(af, bfr[1], acc[t][1], 0, 0, 0);
                acc[t][2] = __builtin_amdgcn_mfma_f32_16x16x32_bf16(af, bfr[2], acc[t][2], 0, 0, 0);
                acc[t][3] = __builtin_amdgcn_mfma_f32_16x16x32_bf16(af, bfr[3], acc[t][3], 0, 0, 0);
            }
        }
        __syncthreads();   // drain prefetch (vmcnt) + protect dbuf swap
    }

    // ---- epilogue: store bf16 res, track min/max (exclude padding rows) ----
    float mn = 3.4e38f, mx = -3.4e38f;
    __hip_bfloat16* rb = res + (size_t)b * NS * NW;
    #pragma unroll
    for (int t = 0; t < 7; ++t) {
        #pragma unroll
        for (int nt = 0; nt < 4; ++nt) {
            #pragma unroll
            for (int r = 0; r < 4; ++r) {
                int row = 16 * t + 4 * g + r;     // C/D: col=lane&15, row=4*(lane>>4)+r
                if (row < NS) {
                    float v = acc[t][nt][r];
                    mn = fminf(mn, v);
                    mx = fmaxf(mx, v);
                    rb[(size_t)row * NW + wbase + 16 * nt + n] = __float2bfloat16(v);
                }
            }
        }
    }

    for (int off = 32; off > 0; off >>= 1) {
        mn = fminf(mn, __shfl_down(mn, off));
        mx = fmaxf(mx, __shfl_down(mx, off));
    }
    if (lane == 0) { smn[wv] = mn; smx[wv] = mx; }
    __syncthreads();
    if (tid == 0) {
        float bmn = fminf(fminf(smn[0], smn[1]), fminf(smn[2], smn[3]));
        float bmx = fmaxf(fmaxf(smx[0], smx[1]), fmaxf(smx[2], smx[3]));
        atomicMin(&mm[b], encf(bmn));
        atomicMax(&mm[NB + b], encf(bmx));
    }
}

// Bilinear resize (101,1024)->(200,200), jax.image.resize semantics
__global__ __launch_bounds__(256) void resize_kernel(
        const __hip_bfloat16* __restrict__ res, const unsigned* __restrict__ mm,
        float* __restrict__ out) {
    const int idx = blockIdx.x * 256 + threadIdx.x;
    if (idx >= NB * OH * OW) return;
    const int j = idx % OW;
    const int rem = idx / OW;
    const int i = rem % OH;
    const int b = rem / OH;

    const float mn = decf(mm[b]);
    const float mx = decf(mm[NB + b]);
    const float inv = 1.0f / (mx - mn);

    const float y = (i + 0.5f) * (101.0f / 200.0f) - 0.5f;
    const float xx = (j + 0.5f) * (1024.0f / 200.0f) - 0.5f;
    const float yf = floorf(y), xf = floorf(xx);
    const float fy = y - yf, fx = xx - xf;
    int i0 = (int)yf, j0 = (int)xf;
    int i1 = i0 + 1, j1 = j0 + 1;
    i0 = max(0, min(NS - 1, i0)); i1 = max(0, min(NS - 1, i1));
    j0 = max(0, min(NW - 1, j0)); j1 = max(0, min(NW - 1, j1));

    const __hip_bfloat16* rbp = res + (size_t)b * NS * NW;
    const float v00 = __bfloat162float(rbp[i0 * NW + j0]);
    const float v01 = __bfloat162float(rbp[i0 * NW + j1]);
    const float v10 = __bfloat162float(rbp[i1 * NW + j0]);
    const float v11 = __bfloat162float(rbp[i1 * NW + j1]);
    const float v = (1.f - fy) * ((1.f - fx) * v00 + fx * v01)
                  + fy * ((1.f - fx) * v10 + fx * v11);
    out[idx] = (v - mn) * inv;
}

extern "C" void kernel_launch(void* const* d_in, const int* in_sizes, int n_in,
                              void* d_out, int out_size, void* d_ws, size_t ws_size,
                              hipStream_t stream) {
    const float* x = (const float*)d_in[0];   // (128,1024) f32
    const float* K = (const float*)d_in[1];   // (101,1024) f32
    float* out = (float*)d_out;               // (128,200,200,1) f32

    char* ws = (char*)d_ws;
    __hip_bfloat16* res = (__hip_bfloat16*)ws;                       // 26.48 MB
    size_t off = (size_t)NB * NS * NW * 2;
    unsigned* mm = (unsigned*)(ws + off);                            // 1 KB
    ushort* Kbf = (ushort*)(ws + off + 1024);                        // 224 KB

    hipLaunchKernelGGL(prep_kernel, dim3(113), dim3(256), 0, stream, K, Kbf, mm);
    hipLaunchKernelGGL(conv_mfma, dim3(512), dim3(256), 0, stream,
                       x, Kbf, res, mm);
    const int total = NB * OH * OW;
    hipLaunchKernelGGL(resize_kernel, dim3((total + 255) / 256), dim3(256), 0, stream,
                       res, mm, out);
}

// Round 3
// 107.006 us; speedup vs baseline: 2.9863x; 1.2264x over previous
//
#include <hip/hip_runtime.h>
#include <hip/hip_bf16.h>

#define NB 128
#define NS 101
#define NW 1024
#define OH 200
#define OW 200

typedef __bf16 bf16x8 __attribute__((ext_vector_type(8)));
typedef float f32x4 __attribute__((ext_vector_type(4)));

__device__ __forceinline__ void gload_lds16(const void* gsrc, void* ldst) {
    __builtin_amdgcn_global_load_lds(
        (const __attribute__((address_space(1))) void*)gsrc,
        (__attribute__((address_space(3))) void*)ldst, 16, 0, 0);
}

// ---- sortable-uint encode for float atomics ----
__device__ __forceinline__ unsigned encf(float f) {
    unsigned u = __float_as_uint(f);
    return (u & 0x80000000u) ? ~u : (u | 0x80000000u);
}
__device__ __forceinline__ float decf(unsigned e) {
    unsigned u = (e & 0x80000000u) ? (e ^ 0x80000000u) : ~e;
    return __uint_as_float(u);
}

// prep: Kbf[112][1024] bf16 (rows >=101 zero) + init per-batch min/max slots
__global__ __launch_bounds__(256) void prep_kernel(const float* __restrict__ K,
                                                   ushort* __restrict__ Kbf,
                                                   unsigned* __restrict__ mm) {
    int blk = blockIdx.x;
    if (blk < 112) {
        int c = threadIdx.x * 4;
        float4 v = make_float4(0.f, 0.f, 0.f, 0.f);
        if (blk < NS) v = *(const float4*)(K + (size_t)blk * NW + c);
        ushort4 o;
        __hip_bfloat16 h;
        h = __float2bfloat16(v.x); o.x = reinterpret_cast<const ushort&>(h);
        h = __float2bfloat16(v.y); o.y = reinterpret_cast<const ushort&>(h);
        h = __float2bfloat16(v.z); o.z = reinterpret_cast<const ushort&>(h);
        h = __float2bfloat16(v.w); o.w = reinterpret_cast<const ushort&>(h);
        *(ushort4*)(Kbf + (size_t)blk * NW + c) = o;
    } else {
        int t = threadIdx.x;
        mm[t] = (t < NB) ? 0xFFFFFFFFu : 0u;
    }
}

// Active s-ranges per 16-row tile t (6*smax+2 truncation, same as verified r2):
// t: 0[12,19] 1[9,22] 2[6,25] 3[3,28] 4[0,31] 5[0,31] 6[0,31]
// classA = t{0,1,3,4} -> 80 tiles, bases {0,8,22,48}
// classB = t{2,5,6}   -> 84 tiles, bases {0,20,52}

#define STAGE_T(t, lo, hi, base)                                              \
    _Pragma("unroll")                                                         \
    for (int s = (lo); s <= (hi); ++s) {                                      \
        if ((((base) + s - (lo)) & 7) == wv)                                  \
            gload_lds16(Kbf + (size_t)(16 * (t) + n) * NW + 32 * s + 8 * g,   \
                        &A_lds[((base) + s - (lo)) * 512]);                   \
    }

#define MFMA_T(t, lo, hi, base, ti)                                           \
    if (s >= (lo) && s <= (hi)) {                                             \
        bf16x8 af = *(const bf16x8*)&A_lds[((base) + s - (lo)) * 512 + lane * 8]; \
        _Pragma("unroll")                                                     \
        for (int nt = 0; nt < 8; ++nt)                                        \
            acc[ti][nt] = __builtin_amdgcn_mfma_f32_16x16x32_bf16(            \
                af, ring[(2 * s - nt) & 7], acc[ti][nt], 0, 0, 0);            \
    }

#define EPI_T(t, ti)                                                          \
    _Pragma("unroll")                                                         \
    for (int nt = 0; nt < 8; ++nt) {                                          \
        _Pragma("unroll")                                                     \
        for (int r = 0; r < 4; ++r) {                                         \
            const int row = 16 * (t) + 4 * g + r;                             \
            if (row < NS) {                                                   \
                float v = acc[ti][nt][r];                                     \
                mn = fminf(mn, v); mx = fmaxf(mx, v);                         \
                rb[(size_t)row * NW + wbase + 16 * nt + n] = __float2bfloat16(v); \
            }                                                                 \
        }                                                                     \
    }

// grid 256: bid<128 -> classA batch bid; bid>=128 -> classB batch bid-128.
// 512 threads = 8 waves; wave wv owns w in [wv*128, wv*128+128).
__global__ __launch_bounds__(512, 2) void conv_mfma(
        const float* __restrict__ x, const ushort* __restrict__ Kbf,
        __hip_bfloat16* __restrict__ res, unsigned* __restrict__ mm) {
    __shared__ __align__(16) ushort A_lds[84 * 512];   // 86016 B
    __shared__ __align__(16) ushort xSh[8 * 2056];     // 32896 B

    const int tid = threadIdx.x;
    const int bid = blockIdx.x;
    const int cls = bid >> 7;
    const int b = bid & 127;
    const int wv = tid >> 6;
    const int lane = tid & 63;
    const int n = lane & 15;
    const int g = lane >> 4;

    // ---- stage reversed padded signal, 8 shifted copies: xSh[d][i]=xR[i+d],
    //      xR[q] = x[1535-q] for q in [512,1536) else 0 ----
    {
        const float* xb = x + (size_t)b * NW;
        for (int idx = tid; idx < 8 * 257; idx += 512) {
            int dlt = idx / 257;
            int i0 = (idx % 257) * 8;
            union { ushort us[8]; uint4 v; } pk;
            #pragma unroll
            for (int j = 0; j < 8; ++j) {
                int ir = i0 + j + dlt;
                float f = (ir >= 512 && ir < 1536) ? xb[1535 - ir] : 0.0f;
                __hip_bfloat16 h = __float2bfloat16(f);
                pk.us[j] = reinterpret_cast<const ushort&>(h);
            }
            *reinterpret_cast<uint4*>(&xSh[dlt * 2056 + i0]) = pk.v;
        }
    }

    // ---- stage A tiles (once per block) ----
    if (cls == 0) {
        STAGE_T(0, 12, 19, 0)
        STAGE_T(1,  9, 22, 8)
        STAGE_T(3,  3, 28, 22)
        STAGE_T(4,  0, 31, 48)
    } else {
        STAGE_T(2,  6, 25, 0)
        STAGE_T(5,  0, 31, 20)
        STAGE_T(6,  0, 31, 52)
    }
    __syncthreads();   // drains vmcnt for global_load_lds + xSh writes

    // ---- B-ring base: lane reads xR[q0..q0+7], q0 = 1023-wbase-n+8g+16f,
    //      from shifted copy dlt=(7-n)&7 (16B-aligned by construction) ----
    const int dlt = (7 - n) & 7;
    const int wbase = wv * 128;
    const ushort* bp = xSh + dlt * 2056 + (1023 - wbase - n + 8 * g - dlt);

    float mn = 3.4e38f, mx = -3.4e38f;
    __hip_bfloat16* rb = res + (size_t)b * NS * NW;

    if (cls == 0) {
        f32x4 acc[4][8];
        #pragma unroll
        for (int ti = 0; ti < 4; ++ti)
            #pragma unroll
            for (int nt = 0; nt < 8; ++nt)
                acc[ti][nt] = (f32x4){0.f, 0.f, 0.f, 0.f};
        bf16x8 ring[8];
        #pragma unroll
        for (int f = -7; f <= 0; ++f)
            ring[f & 7] = *(const bf16x8*)(bp + 16 * f);
        #pragma unroll
        for (int s = 0; s < 32; ++s) {
            if (s > 0) {
                ring[(2 * s - 1) & 7] = *(const bf16x8*)(bp + 16 * (2 * s - 1));
                ring[(2 * s) & 7]     = *(const bf16x8*)(bp + 16 * (2 * s));
            }
            MFMA_T(0, 12, 19, 0, 0)
            MFMA_T(1,  9, 22, 8, 1)
            MFMA_T(3,  3, 28, 22, 2)
            MFMA_T(4,  0, 31, 48, 3)
        }
        EPI_T(0, 0)
        EPI_T(1, 1)
        EPI_T(3, 2)
        EPI_T(4, 3)
    } else {
        f32x4 acc[3][8];
        #pragma unroll
        for (int ti = 0; ti < 3; ++ti)
            #pragma unroll
            for (int nt = 0; nt < 8; ++nt)
                acc[ti][nt] = (f32x4){0.f, 0.f, 0.f, 0.f};
        bf16x8 ring[8];
        #pragma unroll
        for (int f = -7; f <= 0; ++f)
            ring[f & 7] = *(const bf16x8*)(bp + 16 * f);
        #pragma unroll
        for (int s = 0; s < 32; ++s) {
            if (s > 0) {
                ring[(2 * s - 1) & 7] = *(const bf16x8*)(bp + 16 * (2 * s - 1));
                ring[(2 * s) & 7]     = *(const bf16x8*)(bp + 16 * (2 * s));
            }
            MFMA_T(2,  6, 25, 0, 0)
            MFMA_T(5,  0, 31, 20, 1)
            MFMA_T(6,  0, 31, 52, 2)
        }
        EPI_T(2, 0)
        EPI_T(5, 1)
        EPI_T(6, 2)
    }

    // per-wave min/max reduce + one atomic pair per wave
    #pragma unroll
    for (int off = 32; off > 0; off >>= 1) {
        mn = fminf(mn, __shfl_down(mn, off));
        mx = fmaxf(mx, __shfl_down(mx, off));
    }
    if (lane == 0) {
        atomicMin(&mm[b], encf(mn));
        atomicMax(&mm[NB + b], encf(mx));
    }
}

// pass 1: horizontal bilinear 1024 -> 200 (jax semantics), bf16 -> f32 tmp
__global__ __launch_bounds__(256) void resize_h(
        const __hip_bfloat16* __restrict__ res, float* __restrict__ tmp) {
    int idx = blockIdx.x * 256 + threadIdx.x;
    if (idx >= NB * NS * OW) return;
    const int j = idx % OW;
    const int s = (idx / OW) % NS;
    const int b = idx / (OW * NS);
    const float xx = (j + 0.5f) * (1024.0f / 200.0f) - 0.5f;
    const float xf = floorf(xx);
    const float fx = xx - xf;
    int j0 = (int)xf, j1 = j0 + 1;
    j0 = max(0, min(NW - 1, j0)); j1 = max(0, min(NW - 1, j1));
    const __hip_bfloat16* rp = res + ((size_t)b * NS + s) * NW;
    tmp[idx] = (1.f - fx) * __bfloat162float(rp[j0]) + fx * __bfloat162float(rp[j1]);
}

// pass 2: vertical bilinear 101 -> 200 + normalize
__global__ __launch_bounds__(256) void resize_v(
        const float* __restrict__ tmp, const unsigned* __restrict__ mm,
        float* __restrict__ out) {
    int idx = blockIdx.x * 256 + threadIdx.x;
    if (idx >= NB * OH * OW) return;
    const int j = idx % OW;
    const int i = (idx / OW) % OH;
    const int b = idx / (OW * OH);
    const float mn = decf(mm[b]);
    const float inv = 1.0f / (decf(mm[NB + b]) - mn);
    const float y = (i + 0.5f) * (101.0f / 200.0f) - 0.5f;
    const float yf = floorf(y);
    const float fy = y - yf;
    int i0 = (int)yf, i1 = i0 + 1;
    i0 = max(0, min(NS - 1, i0)); i1 = max(0, min(NS - 1, i1));
    const float* tp = tmp + (size_t)b * NS * OW;
    float v = (1.f - fy) * tp[i0 * OW + j] + fy * tp[i1 * OW + j];
    out[idx] = (v - mn) * inv;
}

extern "C" void kernel_launch(void* const* d_in, const int* in_sizes, int n_in,
                              void* d_out, int out_size, void* d_ws, size_t ws_size,
                              hipStream_t stream) {
    const float* x = (const float*)d_in[0];   // (128,1024) f32
    const float* K = (const float*)d_in[1];   // (101,1024) f32
    float* out = (float*)d_out;               // (128,200,200,1) f32

    char* ws = (char*)d_ws;
    __hip_bfloat16* res = (__hip_bfloat16*)ws;                 // 26.48 MB
    size_t off = (size_t)NB * NS * NW * 2;
    unsigned* mm = (unsigned*)(ws + off);                      // 1 KB
    ushort* Kbf = (ushort*)(ws + off + 1024);                  // 229 KB
    float* tmp = (float*)(ws + off + 1024 + (size_t)112 * NW * 2);  // 10.34 MB

    hipLaunchKernelGGL(prep_kernel, dim3(113), dim3(256), 0, stream, K, Kbf, mm);
    hipLaunchKernelGGL(conv_mfma, dim3(256), dim3(512), 0, stream, x, Kbf, res, mm);
    const int t1 = NB * NS * OW;
    hipLaunchKernelGGL(resize_h, dim3((t1 + 255) / 256), dim3(256), 0, stream, res, tmp);
    const int t2 = NB * OH * OW;
    hipLaunchKernelGGL(resize_v, dim3((t2 + 255) / 256), dim3(256), 0, stream, tmp, mm, out);
}

// Round 4
// 103.557 us; speedup vs baseline: 3.0858x; 1.0333x over previous
//
#include <hip/hip_runtime.h>
#include <hip/hip_bf16.h>

#define NB 128
#define NS 101
#define NW 1024
#define OH 200
#define OW 200
#define EPS 1034   // epi row stride (floats): 4*EPS % 32 = 8 -> conflict-free dump

typedef __bf16 bf16x8 __attribute__((ext_vector_type(8)));
typedef float f32x4 __attribute__((ext_vector_type(4)));

__device__ __forceinline__ void gload_lds16(const void* gsrc, void* ldst) {
    __builtin_amdgcn_global_load_lds(
        (const __attribute__((address_space(1))) void*)gsrc,
        (__attribute__((address_space(3))) void*)ldst, 16, 0, 0);
}

// ---- sortable-uint encode for float atomics ----
__device__ __forceinline__ unsigned encf(float f) {
    unsigned u = __float_as_uint(f);
    return (u & 0x80000000u) ? ~u : (u | 0x80000000u);
}
__device__ __forceinline__ float decf(unsigned e) {
    unsigned u = (e & 0x80000000u) ? (e ^ 0x80000000u) : ~e;
    return __uint_as_float(u);
}

// prep: Kbf[112][1024] bf16 (rows >=101 zero) + init per-batch min/max slots
__global__ __launch_bounds__(256) void prep_kernel(const float* __restrict__ K,
                                                   ushort* __restrict__ Kbf,
                                                   unsigned* __restrict__ mm) {
    int blk = blockIdx.x;
    if (blk < 112) {
        int c = threadIdx.x * 4;
        float4 v = make_float4(0.f, 0.f, 0.f, 0.f);
        if (blk < NS) v = *(const float4*)(K + (size_t)blk * NW + c);
        ushort4 o;
        __hip_bfloat16 h;
        h = __float2bfloat16(v.x); o.x = reinterpret_cast<const ushort&>(h);
        h = __float2bfloat16(v.y); o.y = reinterpret_cast<const ushort&>(h);
        h = __float2bfloat16(v.z); o.z = reinterpret_cast<const ushort&>(h);
        h = __float2bfloat16(v.w); o.w = reinterpret_cast<const ushort&>(h);
        *(ushort4*)(Kbf + (size_t)blk * NW + c) = o;
    } else {
        int t = threadIdx.x;
        mm[t] = (t < NB) ? 0xFFFFFFFFu : 0u;
    }
}

// Active s-ranges per 16-row tile t (6*smax+2 truncation, verified r2/r3):
// t: 0[12,19] 1[9,22] 2[6,25] 3[3,28] 4[0,31] 5[0,31] 6[0,31]
// classA = t{0,1,3,4} -> 80 tiles, bases {0,8,22,48}
// classB = t{2,5,6}   -> 84 tiles, bases {0,20,52}

#define STAGE_T(t, lo, hi, base)                                              \
    _Pragma("unroll")                                                         \
    for (int s = (lo); s <= (hi); ++s) {                                      \
        if ((((base) + s - (lo)) & 7) == wv)                                  \
            gload_lds16(Kbf + (size_t)(16 * (t) + n) * NW + 32 * s + 8 * g,   \
                        &A_lds[((base) + s - (lo)) * 512]);                   \
    }

#define MFMA_T(t, lo, hi, base, ti)                                           \
    if (s >= (lo) && s <= (hi)) {                                             \
        bf16x8 af = *(const bf16x8*)&A_lds[((base) + s - (lo)) * 512 + lane * 8]; \
        _Pragma("unroll")                                                     \
        for (int nt = 0; nt < 8; ++nt)                                        \
            acc[ti][nt] = __builtin_amdgcn_mfma_f32_16x16x32_bf16(            \
                af, ring[(2 * s - nt) & 7], acc[ti][nt], 0, 0, 0);            \
    }

// Epilogue per t-tile: dump acc -> epi LDS (f32), track min/max, then
// horizontal bilinear 1024 -> 200 from LDS, write f32 tmp[b][srow][200].
#define EPI_T(t, ti)                                                          \
    {                                                                         \
        _Pragma("unroll")                                                     \
        for (int nt = 0; nt < 8; ++nt) {                                      \
            _Pragma("unroll")                                                 \
            for (int r = 0; r < 4; ++r) {                                     \
                const int row16 = 4 * g + r;                                  \
                float v = acc[ti][nt][r];                                     \
                if (16 * (t) + row16 < NS) { mn = fminf(mn, v); mx = fmaxf(mx, v); } \
                epi[row16 * EPS + wbase + 16 * nt + n] = v;                   \
            }                                                                 \
        }                                                                     \
        __syncthreads();                                                      \
        for (int idx = tid; idx < 16 * OW; idx += 512) {                      \
            const int row16 = idx / OW;                                       \
            const int j = idx % OW;                                           \
            const int srow = 16 * (t) + row16;                                \
            if (srow < NS) {                                                  \
                const float xx = (j + 0.5f) * (1024.0f / 200.0f) - 0.5f;      \
                const float xf = floorf(xx);                                  \
                const float fx = xx - xf;                                     \
                int j0 = (int)xf, j1 = j0 + 1;                                \
                j0 = max(0, min(NW - 1, j0)); j1 = max(0, min(NW - 1, j1));   \
                tmp[((size_t)b * NS + srow) * OW + j] =                       \
                    (1.f - fx) * epi[row16 * EPS + j0] + fx * epi[row16 * EPS + j1]; \
            }                                                                 \
        }                                                                     \
        __syncthreads();                                                      \
    }

// grid 256: bid<128 -> classA batch bid; bid>=128 -> classB batch bid-128.
// 512 threads = 8 waves; wave wv owns w in [wv*128, wv*128+128).
__global__ __launch_bounds__(512, 1) void conv_mfma(
        const float* __restrict__ x, const ushort* __restrict__ Kbf,
        float* __restrict__ tmp, unsigned* __restrict__ mm) {
    // overlay: main phase {A_lds 86016B | xSh 32896B}; epilogue {epi 66176B}
    __shared__ __align__(16) char smem[118912];
    ushort* A_lds = (ushort*)smem;
    ushort* xSh = (ushort*)(smem + 86016);
    float* epi = (float*)smem;

    const int tid = threadIdx.x;
    const int bid = blockIdx.x;
    const int cls = bid >> 7;
    const int b = bid & 127;
    const int wv = tid >> 6;
    const int lane = tid & 63;
    const int n = lane & 15;
    const int g = lane >> 4;

    // ---- stage reversed padded signal, 8 shifted copies: xSh[d][i]=xR[i+d],
    //      xR[q] = x[1535-q] for q in [512,1536) else 0 ----
    {
        const float* xb = x + (size_t)b * NW;
        for (int idx = tid; idx < 8 * 257; idx += 512) {
            int dlt = idx / 257;
            int i0 = (idx % 257) * 8;
            union { ushort us[8]; uint4 v; } pk;
            #pragma unroll
            for (int j = 0; j < 8; ++j) {
                int ir = i0 + j + dlt;
                float f = (ir >= 512 && ir < 1536) ? xb[1535 - ir] : 0.0f;
                __hip_bfloat16 h = __float2bfloat16(f);
                pk.us[j] = reinterpret_cast<const ushort&>(h);
            }
            *reinterpret_cast<uint4*>(&xSh[dlt * 2056 + i0]) = pk.v;
        }
    }

    // ---- stage A tiles (once per block) ----
    if (cls == 0) {
        STAGE_T(0, 12, 19, 0)
        STAGE_T(1,  9, 22, 8)
        STAGE_T(3,  3, 28, 22)
        STAGE_T(4,  0, 31, 48)
    } else {
        STAGE_T(2,  6, 25, 0)
        STAGE_T(5,  0, 31, 20)
        STAGE_T(6,  0, 31, 52)
    }
    __syncthreads();   // drains vmcnt for global_load_lds + xSh writes

    // ---- B-ring base: lane reads xR[q0..q0+7], q0 = 1023-wbase-n+8g+16f,
    //      from shifted copy dlt=(7-n)&7 (16B-aligned by construction) ----
    const int dlt = (7 - n) & 7;
    const int wbase = wv * 128;
    const ushort* bp = xSh + dlt * 2056 + (1023 - wbase - n + 8 * g - dlt);

    float mn = 3.4e38f, mx = -3.4e38f;

    if (cls == 0) {
        f32x4 acc[4][8];
        #pragma unroll
        for (int ti = 0; ti < 4; ++ti)
            #pragma unroll
            for (int nt = 0; nt < 8; ++nt)
                acc[ti][nt] = (f32x4){0.f, 0.f, 0.f, 0.f};
        bf16x8 ring[8];
        #pragma unroll
        for (int f = -7; f <= 0; ++f)
            ring[f & 7] = *(const bf16x8*)(bp + 16 * f);
        #pragma unroll
        for (int s = 0; s < 32; ++s) {
            if (s > 0) {
                ring[(2 * s - 1) & 7] = *(const bf16x8*)(bp + 16 * (2 * s - 1));
                ring[(2 * s) & 7]     = *(const bf16x8*)(bp + 16 * (2 * s));
            }
            MFMA_T(0, 12, 19, 0, 0)
            MFMA_T(1,  9, 22, 8, 1)
            MFMA_T(3,  3, 28, 22, 2)
            MFMA_T(4,  0, 31, 48, 3)
        }
        __syncthreads();   // all waves done with A_lds/xSh before epi overlay
        EPI_T(0, 0)
        EPI_T(1, 1)
        EPI_T(3, 2)
        EPI_T(4, 3)
    } else {
        f32x4 acc[3][8];
        #pragma unroll
        for (int ti = 0; ti < 3; ++ti)
            #pragma unroll
            for (int nt = 0; nt < 8; ++nt)
                acc[ti][nt] = (f32x4){0.f, 0.f, 0.f, 0.f};
        bf16x8 ring[8];
        #pragma unroll
        for (int f = -7; f <= 0; ++f)
            ring[f & 7] = *(const bf16x8*)(bp + 16 * f);
        #pragma unroll
        for (int s = 0; s < 32; ++s) {
            if (s > 0) {
                ring[(2 * s - 1) & 7] = *(const bf16x8*)(bp + 16 * (2 * s - 1));
                ring[(2 * s) & 7]     = *(const bf16x8*)(bp + 16 * (2 * s));
            }
            MFMA_T(2,  6, 25, 0, 0)
            MFMA_T(5,  0, 31, 20, 1)
            MFMA_T(6,  0, 31, 52, 2)
        }
        __syncthreads();
        EPI_T(2, 0)
        EPI_T(5, 1)
        EPI_T(6, 2)
    }

    // per-wave min/max reduce + one atomic pair per wave
    #pragma unroll
    for (int off = 32; off > 0; off >>= 1) {
        mn = fminf(mn, __shfl_down(mn, off));
        mx = fmaxf(mx, __shfl_down(mx, off));
    }
    if (lane == 0) {
        atomicMin(&mm[b], encf(mn));
        atomicMax(&mm[NB + b], encf(mx));
    }
}

// vertical bilinear 101 -> 200 + normalize (jax semantics)
__global__ __launch_bounds__(256) void resize_v(
        const float* __restrict__ tmp, const unsigned* __restrict__ mm,
        float* __restrict__ out) {
    int idx = blockIdx.x * 256 + threadIdx.x;
    if (idx >= NB * OH * OW) return;
    const int j = idx % OW;
    const int i = (idx / OW) % OH;
    const int b = idx / (OW * OH);
    const float mn = decf(mm[b]);
    const float inv = 1.0f / (decf(mm[NB + b]) - mn);
    const float y = (i + 0.5f) * (101.0f / 200.0f) - 0.5f;
    const float yf = floorf(y);
    const float fy = y - yf;
    int i0 = (int)yf, i1 = i0 + 1;
    i0 = max(0, min(NS - 1, i0)); i1 = max(0, min(NS - 1, i1));
    const float* tp = tmp + (size_t)b * NS * OW;
    float v = (1.f - fy) * tp[i0 * OW + j] + fy * tp[i1 * OW + j];
    out[idx] = (v - mn) * inv;
}

extern "C" void kernel_launch(void* const* d_in, const int* in_sizes, int n_in,
                              void* d_out, int out_size, void* d_ws, size_t ws_size,
                              hipStream_t stream) {
    const float* x = (const float*)d_in[0];   // (128,1024) f32
    const float* K = (const float*)d_in[1];   // (101,1024) f32
    float* out = (float*)d_out;               // (128,200,200,1) f32

    char* ws = (char*)d_ws;
    unsigned* mm = (unsigned*)ws;                              // 1 KB
    ushort* Kbf = (ushort*)(ws + 1024);                        // 229376 B
    float* tmp = (float*)(ws + 1024 + (size_t)112 * NW * 2);   // 10.34 MB

    hipLaunchKernelGGL(prep_kernel, dim3(113), dim3(256), 0, stream, K, Kbf, mm);
    hipLaunchKernelGGL(conv_mfma, dim3(256), dim3(512), 0, stream, x, Kbf, tmp, mm);
    const int t2 = NB * OH * OW;
    hipLaunchKernelGGL(resize_v, dim3((t2 + 255) / 256), dim3(256), 0, stream, tmp, mm, out);
}

// Round 5
// 99.548 us; speedup vs baseline: 3.2101x; 1.0403x over previous
//
#include <hip/hip_runtime.h>
#include <hip/hip_bf16.h>

#define NB 128
#define NS 101
#define NW 1024
#define OH 200
#define OW 200
#define EPS 1034   // epi row stride (floats): 4*EPS % 32 = 8 -> conflict-free dump

typedef __bf16 bf16x8 __attribute__((ext_vector_type(8)));
typedef float f32x4 __attribute__((ext_vector_type(4)));

// Active s-ranges per 16-row tile t (6*smax+2 truncation, verified r2-r4):
// t: 0[12,19] 1[9,22] 2[6,25] 3[3,28] 4[0,31] 5[0,31] 6[0,31]
// classA = t{0,1,3,4} -> 80 tiles, bases {0,8,22,48}; rows 0-31,48-79
// classB = t{2,5,6}   -> 84 tiles, bases {0,20,52};  rows 32-47,80-111

// Stage one K tile (f32 -> bf16 in-flight); rows >= NS are zeroed.
#define STAGE_T(t, lo, hi, base)                                              \
    _Pragma("unroll")                                                         \
    for (int s = (lo); s <= (hi); ++s) {                                      \
        if ((((base) + s - (lo)) & 7) == wv) {                                \
            const int row = 16 * (t) + n;                                     \
            union { ushort us[8]; uint4 v; } pk;                              \
            pk.v = (uint4){0u, 0u, 0u, 0u};                                   \
            if (row < NS) {                                                   \
                const float* kp = K + (size_t)row * NW + 32 * s + 8 * g;      \
                const float4 f0 = *(const float4*)kp;                         \
                const float4 f1 = *(const float4*)(kp + 4);                   \
                __hip_bfloat16 h;                                             \
                h = __float2bfloat16(f0.x); pk.us[0] = reinterpret_cast<const ushort&>(h); \
                h = __float2bfloat16(f0.y); pk.us[1] = reinterpret_cast<const ushort&>(h); \
                h = __float2bfloat16(f0.z); pk.us[2] = reinterpret_cast<const ushort&>(h); \
                h = __float2bfloat16(f0.w); pk.us[3] = reinterpret_cast<const ushort&>(h); \
                h = __float2bfloat16(f1.x); pk.us[4] = reinterpret_cast<const ushort&>(h); \
                h = __float2bfloat16(f1.y); pk.us[5] = reinterpret_cast<const ushort&>(h); \
                h = __float2bfloat16(f1.z); pk.us[6] = reinterpret_cast<const ushort&>(h); \
                h = __float2bfloat16(f1.w); pk.us[7] = reinterpret_cast<const ushort&>(h); \
            }                                                                 \
            *(uint4*)&A_lds[((base) + s - (lo)) * 512 + lane * 8] = pk.v;     \
        }                                                                     \
    }

#define MFMA_T(t, lo, hi, base, ti)                                           \
    if (s >= (lo) && s <= (hi)) {                                             \
        bf16x8 af = *(const bf16x8*)&A_lds[((base) + s - (lo)) * 512 + lane * 8]; \
        _Pragma("unroll")                                                     \
        for (int nt = 0; nt < 8; ++nt)                                        \
            acc[ti][nt] = __builtin_amdgcn_mfma_f32_16x16x32_bf16(            \
                af, ring[(2 * s - nt) & 7], acc[ti][nt], 0, 0, 0);            \
    }

// Epilogue per t-tile: dump acc -> epi LDS (f32), track min/max, then
// horizontal bilinear 1024 -> 200 from LDS, write bf16 tmp[b][srow][200].
#define EPI_T(t, ti)                                                          \
    {                                                                         \
        _Pragma("unroll")                                                     \
        for (int nt = 0; nt < 8; ++nt) {                                      \
            _Pragma("unroll")                                                 \
            for (int r = 0; r < 4; ++r) {                                     \
                const int row16 = 4 * g + r;                                  \
                float v = acc[ti][nt][r];                                     \
                if (16 * (t) + row16 < NS) { mn = fminf(mn, v); mx = fmaxf(mx, v); } \
                epi[row16 * EPS + wbase + 16 * nt + n] = v;                   \
            }                                                                 \
        }                                                                     \
        __syncthreads();                                                      \
        for (int idx = tid; idx < 16 * OW; idx += 512) {                      \
            const int row16 = idx / OW;                                       \
            const int j = idx % OW;                                           \
            const int srow = 16 * (t) + row16;                                \
            if (srow < NS) {                                                  \
                const float xx = (j + 0.5f) * (1024.0f / 200.0f) - 0.5f;      \
                const float xf = floorf(xx);                                  \
                const float fx = xx - xf;                                     \
                int j0 = (int)xf, j1 = j0 + 1;                                \
                j0 = max(0, min(NW - 1, j0)); j1 = max(0, min(NW - 1, j1));   \
                tmp[((size_t)b * NS + srow) * OW + j] = __float2bfloat16(     \
                    (1.f - fx) * epi[row16 * EPS + j0] + fx * epi[row16 * EPS + j1]); \
            }                                                                 \
        }                                                                     \
        __syncthreads();                                                      \
    }

// grid 256: bid<128 -> classA batch bid; bid>=128 -> classB batch bid-128.
// 512 threads = 8 waves; wave wv owns w in [wv*128, wv*128+128).
// mm layout (plain f32 stores, disjoint per block, no init needed):
//   mm[cls*256 + b] = min, mm[cls*256 + 128 + b] = max.
__global__ __launch_bounds__(512, 1) void conv_mfma(
        const float* __restrict__ x, const float* __restrict__ K,
        __hip_bfloat16* __restrict__ tmp, float* __restrict__ mm) {
    // overlay: main phase {A_lds 86016B | xSh 32896B}; epilogue {epi 66176B}
    __shared__ __align__(16) char smem[118912];
    ushort* A_lds = (ushort*)smem;
    ushort* xSh = (ushort*)(smem + 86016);
    float* epi = (float*)smem;
    __shared__ float smn[8], smx[8];

    const int tid = threadIdx.x;
    const int bid = blockIdx.x;
    const int cls = bid >> 7;
    const int b = bid & 127;
    const int wv = tid >> 6;
    const int lane = tid & 63;
    const int n = lane & 15;
    const int g = lane >> 4;

    // ---- stage reversed padded signal, 8 shifted copies: xSh[d][i]=xR[i+d],
    //      xR[q] = x[1535-q] for q in [512,1536) else 0 ----
    {
        const float* xb = x + (size_t)b * NW;
        for (int idx = tid; idx < 8 * 257; idx += 512) {
            int dlt = idx / 257;
            int i0 = (idx % 257) * 8;
            union { ushort us[8]; uint4 v; } pk;
            #pragma unroll
            for (int j = 0; j < 8; ++j) {
                int ir = i0 + j + dlt;
                float f = (ir >= 512 && ir < 1536) ? xb[1535 - ir] : 0.0f;
                __hip_bfloat16 h = __float2bfloat16(f);
                pk.us[j] = reinterpret_cast<const ushort&>(h);
            }
            *reinterpret_cast<uint4*>(&xSh[dlt * 2056 + i0]) = pk.v;
        }
    }

    // ---- stage A tiles (f32 K -> bf16 LDS, once per block) ----
    if (cls == 0) {
        STAGE_T(0, 12, 19, 0)
        STAGE_T(1,  9, 22, 8)
        STAGE_T(3,  3, 28, 22)
        STAGE_T(4,  0, 31, 48)
    } else {
        STAGE_T(2,  6, 25, 0)
        STAGE_T(5,  0, 31, 20)
        STAGE_T(6,  0, 31, 52)
    }
    __syncthreads();   // all ds_writes (A_lds + xSh) visible

    // ---- B-ring base: lane reads xR[q0..q0+7], q0 = 1023-wbase-n+8g+16f,
    //      from shifted copy dlt=(7-n)&7 (16B-aligned by construction) ----
    const int dlt = (7 - n) & 7;
    const int wbase = wv * 128;
    const ushort* bp = xSh + dlt * 2056 + (1023 - wbase - n + 8 * g - dlt);

    float mn = 3.4e38f, mx = -3.4e38f;

    if (cls == 0) {
        f32x4 acc[4][8];
        #pragma unroll
        for (int ti = 0; ti < 4; ++ti)
            #pragma unroll
            for (int nt = 0; nt < 8; ++nt)
                acc[ti][nt] = (f32x4){0.f, 0.f, 0.f, 0.f};
        bf16x8 ring[8];
        #pragma unroll
        for (int f = -7; f <= 0; ++f)
            ring[f & 7] = *(const bf16x8*)(bp + 16 * f);
        #pragma unroll
        for (int s = 0; s < 32; ++s) {
            if (s > 0) {
                ring[(2 * s - 1) & 7] = *(const bf16x8*)(bp + 16 * (2 * s - 1));
                ring[(2 * s) & 7]     = *(const bf16x8*)(bp + 16 * (2 * s));
            }
            MFMA_T(0, 12, 19, 0, 0)
            MFMA_T(1,  9, 22, 8, 1)
            MFMA_T(3,  3, 28, 22, 2)
            MFMA_T(4,  0, 31, 48, 3)
        }
        __syncthreads();   // all waves done with A_lds/xSh before epi overlay
        EPI_T(0, 0)
        EPI_T(1, 1)
        EPI_T(3, 2)
        EPI_T(4, 3)
    } else {
        f32x4 acc[3][8];
        #pragma unroll
        for (int ti = 0; ti < 3; ++ti)
            #pragma unroll
            for (int nt = 0; nt < 8; ++nt)
                acc[ti][nt] = (f32x4){0.f, 0.f, 0.f, 0.f};
        bf16x8 ring[8];
        #pragma unroll
        for (int f = -7; f <= 0; ++f)
            ring[f & 7] = *(const bf16x8*)(bp + 16 * f);
        #pragma unroll
        for (int s = 0; s < 32; ++s) {
            if (s > 0) {
                ring[(2 * s - 1) & 7] = *(const bf16x8*)(bp + 16 * (2 * s - 1));
                ring[(2 * s) & 7]     = *(const bf16x8*)(bp + 16 * (2 * s));
            }
            MFMA_T(2,  6, 25, 0, 0)
            MFMA_T(5,  0, 31, 20, 1)
            MFMA_T(6,  0, 31, 52, 2)
        }
        __syncthreads();
        EPI_T(2, 0)
        EPI_T(5, 1)
        EPI_T(6, 2)
    }

    // block-level min/max reduce, one plain store pair per block (no atomics)
    #pragma unroll
    for (int off = 32; off > 0; off >>= 1) {
        mn = fminf(mn, __shfl_down(mn, off));
        mx = fmaxf(mx, __shfl_down(mx, off));
    }
    if (lane == 0) { smn[wv] = mn; smx[wv] = mx; }
    __syncthreads();
    if (tid == 0) {
        float bmn = smn[0], bmx = smx[0];
        #pragma unroll
        for (int w = 1; w < 8; ++w) {
            bmn = fminf(bmn, smn[w]);
            bmx = fmaxf(bmx, smx[w]);
        }
        mm[cls * 256 + b] = bmn;
        mm[cls * 256 + 128 + b] = bmx;
    }
}

// vertical bilinear 101 -> 200 + normalize (jax semantics)
__global__ __launch_bounds__(256) void resize_v(
        const __hip_bfloat16* __restrict__ tmp, const float* __restrict__ mm,
        float* __restrict__ out) {
    int idx = blockIdx.x * 256 + threadIdx.x;
    if (idx >= NB * OH * OW) return;
    const int j = idx % OW;
    const int i = (idx / OW) % OH;
    const int b = idx / (OW * OH);
    const float mn = fminf(mm[b], mm[256 + b]);
    const float mx = fmaxf(mm[128 + b], mm[384 + b]);
    const float inv = 1.0f / (mx - mn);
    const float y = (i + 0.5f) * (101.0f / 200.0f) - 0.5f;
    const float yf = floorf(y);
    const float fy = y - yf;
    int i0 = (int)yf, i1 = i0 + 1;
    i0 = max(0, min(NS - 1, i0)); i1 = max(0, min(NS - 1, i1));
    const __hip_bfloat16* tp = tmp + (size_t)b * NS * OW;
    float v = (1.f - fy) * __bfloat162float(tp[i0 * OW + j])
            + fy * __bfloat162float(tp[i1 * OW + j]);
    out[idx] = (v - mn) * inv;
}

extern "C" void kernel_launch(void* const* d_in, const int* in_sizes, int n_in,
                              void* d_out, int out_size, void* d_ws, size_t ws_size,
                              hipStream_t stream) {
    const float* x = (const float*)d_in[0];   // (128,1024) f32
    const float* K = (const float*)d_in[1];   // (101,1024) f32
    float* out = (float*)d_out;               // (128,200,200,1) f32

    char* ws = (char*)d_ws;
    float* mm = (float*)ws;                               // 2 KB (512 f32)
    __hip_bfloat16* tmp = (__hip_bfloat16*)(ws + 4096);   // 5.17 MB

    hipLaunchKernelGGL(conv_mfma, dim3(256), dim3(512), 0, stream, x, K, tmp, mm);
    const int t2 = NB * OH * OW;
    hipLaunchKernelGGL(resize_v, dim3((t2 + 255) / 256), dim3(256), 0, stream, tmp, mm, out);
}